// Round 15
// baseline (63.087 us; speedup 1.0000x reference)
//
#include <hip/hip_runtime.h>
#include <hip/hip_bf16.h>

#define N_TOTAL 8192
#define B_HALF  4096
#define D       256
#define BM      128
#define NTILES  (N_TOTAL / BM)               // 64
#define NBLK    (NTILES * (NTILES + 1) / 2)  // 2080
#define PREP_BLOCKS 512                       // 16 rows/block, 2 blocks/CU

typedef __bf16 bf16x8v __attribute__((ext_vector_type(8)));
typedef float  f32x4v  __attribute__((ext_vector_type(4)));

__device__ __forceinline__ unsigned short f2bf(float x) {
    unsigned int u = __float_as_uint(x);
    return (unsigned short)((u + 0x7FFFu + ((u >> 16) & 1u)) >> 16);
}
__device__ __forceinline__ float bf2f(unsigned short b) {
    return __uint_as_float(((unsigned int)b) << 16);
}

// ---------------------------------------------------------------------------
// prep: f32 -> bf16 in K-PANEL-MAJOR layout tb2[k>>3][row][k&7], row norms
// sq[], per-block column-sum / sum(sq) partials. NO tickets/atomics/fences —
// every output word fully overwritten every call. 512 blocks (2/CU, 8
// waves/CU) for TLP; 4 rows per wave.
// ---------------------------------------------------------------------------
__global__ void prep_kernel(const float* __restrict__ src,
                            const float* __restrict__ tgt,
                            unsigned short* __restrict__ tb2,
                            float* __restrict__ sq,
                            float* __restrict__ colsum_part,  // [512][256]
                            double* __restrict__ sumsq_part)  // [512]
{
    __shared__ float colpart[4][256];
    __shared__ double wsum[4];
    int tid = threadIdx.x;
    int wv = tid >> 6, ln = tid & 63;
    int row0 = blockIdx.x * 16 + wv * 4;

    float cp0 = 0.f, cp1 = 0.f, cp2 = 0.f, cp3 = 0.f;
    double dsum = 0.0;

    #pragma unroll
    for (int t = 0; t < 4; ++t) {
        int row = row0 + t;
        const float* p = (row < B_HALF) ? (src + (size_t)row * D)
                                        : (tgt + (size_t)(row - B_HALF) * D);
        float4 v = *(const float4*)(p + ln * 4);
        unsigned short b0 = f2bf(v.x), b1 = f2bf(v.y), b2 = f2bf(v.z), b3 = f2bf(v.w);
        float x0 = bf2f(b0), x1 = bf2f(b1), x2 = bf2f(b2), x3 = bf2f(b3);
        ushort4 u; u.x = b0; u.y = b1; u.z = b2; u.w = b3;
        // K-panel-major store: chunk = ln>>1, element base = (ln&1)*4
        *(ushort4*)(tb2 + ((size_t)(ln >> 1) * N_TOTAL + row) * 8 + (ln & 1) * 4) = u;

        cp0 += x0; cp1 += x1; cp2 += x2; cp3 += x3;

        float sqp = x0 * x0 + x1 * x1 + x2 * x2 + x3 * x3;
        #pragma unroll
        for (int off = 32; off; off >>= 1) sqp += __shfl_down(sqp, off, 64);
        if (ln == 0) { sq[row] = sqp; dsum += (double)sqp; }
    }
    colpart[wv][ln * 4 + 0] = cp0;
    colpart[wv][ln * 4 + 1] = cp1;
    colpart[wv][ln * 4 + 2] = cp2;
    colpart[wv][ln * 4 + 3] = cp3;
    if (ln == 0) wsum[wv] = dsum;
    __syncthreads();
    colsum_part[blockIdx.x * 256 + tid] =
        colpart[0][tid] + colpart[1][tid] + colpart[2][tid] + colpart[3][tid];
    if (tid == 0)
        sumsq_part[blockIdx.x] = wsum[0] + wsum[1] + wsum[2] + wsum[3];
}

// ---------------------------------------------------------------------------
// bw: closed-form bandwidth from the partials (1 block, deterministic).
//   sum(L2) = 2n*sum(sq) - 2*||colsum||^2 ; cexp = log2(e)/(16*bw)
// ---------------------------------------------------------------------------
__global__ void bw_kernel(const float* __restrict__ colsum_part,
                          const double* __restrict__ sumsq_part,
                          float* __restrict__ cexp) {
    __shared__ double red1[256], red2[256];
    int tid = threadIdx.x;
    float cs = 0.f;
    #pragma unroll 8
    for (int b = 0; b < PREP_BLOCKS; ++b)
        cs += colsum_part[b * 256 + tid];          // coalesced across threads
    red1[tid] = sumsq_part[tid * 2] + sumsq_part[tid * 2 + 1];
    red2[tid] = (double)cs * (double)cs;
    __syncthreads();
    for (int off = 128; off; off >>= 1) {
        if (tid < off) { red1[tid] += red1[tid + off]; red2[tid] += red2[tid + off]; }
        __syncthreads();
    }
    if (tid == 0) {
        double sl2 = 2.0 * (double)N_TOTAL * red1[0] - 2.0 * red2[0];
        double bw = sl2 / ((double)N_TOTAL * N_TOTAL - (double)N_TOTAL);
        cexp[0] = (float)(1.4426950408889634 / (16.0 * bw));
    }
}

// ---------------------------------------------------------------------------
// mmd [r12-validated, verbatim minus ticket]: lower-triangle 128x128 Gram
// tiles (bijective XCD swizzle), direct-global K-panel fragment loads (1 KB
// contiguous per wave-load), 2-deep register prefetch, no LDS staging, no
// K-loop barriers, scalar fma+exp2 epilogue, plain partials store.
// ---------------------------------------------------------------------------
__global__ __launch_bounds__(256, 3)
void mmd_kernel(const unsigned short* __restrict__ tb2,
                const float* __restrict__ sq,
                const float* __restrict__ cexp_p,
                double* __restrict__ partials) {
    __shared__ float nsqi[BM], nsqj[BM];
    __shared__ float redbuf[4];

    // bijective XCD swizzle (2080 = 8 * 260), then triangle decode
    int bid = blockIdx.x;
    int t = (bid & 7) * (NBLK / 8) + (bid >> 3);
    int r = (int)((sqrtf(8.0f * (float)t + 1.0f) - 1.0f) * 0.5f);
    while ((r + 1) * (r + 2) / 2 <= t) ++r;
    while (r * (r + 1) / 2 > t) --r;
    int c = t - r * (r + 1) / 2;
    int rowBase = r * BM, colBase = c * BM;

    int tid = threadIdx.x;
    int wv = tid >> 6, ln = tid & 63;
    int wr = wv >> 1, wc = wv & 1;
    int lo = ln & 15, hi = ln >> 4;

    float cexp = cexp_p[0];
    // pre-negate and pre-scale: arg = fma(gram, 2*cexp, nsi + nsj) = -L2*cexp
    if (tid < BM) nsqi[tid] = -sq[rowBase + tid] * cexp;
    else          nsqj[tid - BM] = -sq[colBase + (tid - BM)] * cexp;
    __syncthreads();                 // only pre-epilogue barrier

    // fragment base pointers: frag(kk, f) at p + kk*KKSTRIDE + f*256B
    // (lane lo+16*hi: row = base + f*16 + lo, k-chunk = kk*4 + hi)
    const char* pa = (const char*)tb2 +
        ((size_t)hi * N_TOTAL + rowBase + wr * 64 + lo) * 16;
    const char* pb = (const char*)tb2 +
        ((size_t)hi * N_TOTAL + colBase + wc * 64 + lo) * 16;
    const size_t KKSTRIDE = (size_t)4 * N_TOTAL * 16;   // 512 KB

    f32x4v acc[4][4] = {};
    bf16x8v a[2][4], b[2][4];

    #pragma unroll
    for (int mi = 0; mi < 4; ++mi) a[0][mi] = *(const bf16x8v*)(pa + mi * 256);
    #pragma unroll
    for (int ni = 0; ni < 4; ++ni) b[0][ni] = *(const bf16x8v*)(pb + ni * 256);

    #pragma unroll
    for (int kk = 0; kk < 8; ++kk) {        // K = 8 x 32
        const int cur = kk & 1, nxt = cur ^ 1;
        if (kk < 7) {
            const char* qa = pa + (size_t)(kk + 1) * KKSTRIDE;
            const char* qb = pb + (size_t)(kk + 1) * KKSTRIDE;
            #pragma unroll
            for (int mi = 0; mi < 4; ++mi)
                a[nxt][mi] = *(const bf16x8v*)(qa + mi * 256);
            #pragma unroll
            for (int ni = 0; ni < 4; ++ni)
                b[nxt][ni] = *(const bf16x8v*)(qb + ni * 256);
        }
        __builtin_amdgcn_s_setprio(1);
        #pragma unroll
        for (int mi = 0; mi < 4; ++mi)
            #pragma unroll
            for (int ni = 0; ni < 4; ++ni)
                acc[mi][ni] = __builtin_amdgcn_mfma_f32_16x16x32_bf16(
                    a[cur][mi], b[cur][ni], acc[mi][ni], 0, 0, 0);
        __builtin_amdgcn_s_setprio(0);
    }

    // epilogue: arg = gram*2cexp + (nsi + nsj) ; sum = e0+e0^2+e0^4+e0^8+e0^16
    // C/D layout (16x16x32): col = lane&15, row = (lane>>4)*4 + reg
    float c2 = 2.0f * cexp;
    float tacc = 0.f;
    #pragma unroll
    for (int mi = 0; mi < 4; ++mi) {
        float si4[4];
        #pragma unroll
        for (int rg = 0; rg < 4; ++rg)
            si4[rg] = nsqi[wr * 64 + mi * 16 + hi * 4 + rg];
        #pragma unroll
        for (int ni = 0; ni < 4; ++ni) {
            float nsj = nsqj[wc * 64 + ni * 16 + lo];
            #pragma unroll
            for (int rg = 0; rg < 4; ++rg) {
                float arg = __builtin_fmaf(acc[mi][ni][rg], c2, si4[rg] + nsj);
                float e0 = __builtin_amdgcn_exp2f(arg);
                float e2 = e0 * e0, e4 = e2 * e2, e8 = e4 * e4, e16 = e8 * e8;
                tacc += (e0 + e2) + ((e4 + e8) + e16);
            }
        }
    }
    // tile-uniform sign (B_HALF multiple of BM) + triangle weight
    float w = ((r < NTILES / 2) == (c < NTILES / 2)) ? 1.f : -1.f;
    if (r != c) w *= 2.f;
    tacc *= w;

    // block reduction -> plain partial store (no fence, no atomic)
    #pragma unroll
    for (int off = 32; off; off >>= 1) tacc += __shfl_down(tacc, off, 64);
    if (ln == 0) redbuf[wv] = tacc;
    __syncthreads();
    if (tid == 0)
        partials[bid] =
            (double)(redbuf[0] + redbuf[1] + redbuf[2] + redbuf[3]);
}

// ---------------------------------------------------------------------------
__global__ void final_kernel(const double* __restrict__ partials,
                             float* __restrict__ out) {
    __shared__ double dred[256];
    int tid = threadIdx.x;
    double d = 0.0;
    for (int i = tid; i < NBLK; i += 256) d += partials[i];
    dred[tid] = d;
    __syncthreads();
    for (int off = 128; off; off >>= 1) {
        if (tid < off) dred[tid] += dred[tid + off];
        __syncthreads();
    }
    if (tid == 0)
        out[0] = (float)(dred[0] / (5.0 * (double)B_HALF * (double)B_HALF));
}

// ---------------------------------------------------------------------------
extern "C" void kernel_launch(void* const* d_in, const int* in_sizes, int n_in,
                              void* d_out, int out_size, void* d_ws, size_t ws_size,
                              hipStream_t stream) {
    const float* src = (const float*)d_in[0];
    const float* tgt = (const float*)d_in[1];
    float* out = (float*)d_out;
    char* ws = (char*)d_ws;

    // NO memset node, NO tickets, NO atomics: every ws word used is fully
    // overwritten every call before it is read.
    float*  cexp     = (float*)(ws + 192);
    double* ssqpart  = (double*)(ws + 2048);    // 512 f64  (ends 6144)
    float*  sq       = (float*)(ws + 8192);     // 8192 f32 (ends 40960)
    double* partials = (double*)(ws + 40960);   // 2080 f64 (ends 57600)
    float*  cspart   = (float*)(ws + 131072);   // 512*256 f32 (ends 655360)
    unsigned short* tb2 = (unsigned short*)(ws + 1048576);  // 4 MB bf16, K-panel-major

    prep_kernel<<<PREP_BLOCKS, 256, 0, stream>>>(src, tgt, tb2, sq, cspart,
                                                 ssqpart);
    bw_kernel<<<1, 256, 0, stream>>>(cspart, ssqpart, cexp);
    mmd_kernel<<<NBLK, 256, 0, stream>>>(tb2, sq, cexp, partials);
    final_kernel<<<1, 256, 0, stream>>>(partials, out);
}

// Round 17
// 54.957 us; speedup vs baseline: 1.1479x; 1.1479x over previous
//
#include <hip/hip_runtime.h>
#include <hip/hip_bf16.h>

#define N_TOTAL 8192
#define B_HALF  4096
#define D       256
#define BM      128
#define NTILES  (N_TOTAL / BM)               // 64
#define NBLK    (NTILES * (NTILES + 1) / 2)  // 2080
#define PREP_BLOCKS (N_TOTAL / 32)           // 256

typedef __bf16 bf16x8v __attribute__((ext_vector_type(8)));
typedef float  f32x4v  __attribute__((ext_vector_type(4)));

__device__ __forceinline__ unsigned short f2bf(float x) {
    unsigned int u = __float_as_uint(x);
    return (unsigned short)((u + 0x7FFFu + ((u >> 16) & 1u)) >> 16);
}
__device__ __forceinline__ float bf2f(unsigned short b) {
    return __uint_as_float(((unsigned int)b) << 16);
}

// ---------------------------------------------------------------------------
// prep [r10-validated, best-measured]: f32 -> bf16 in K-PANEL-MAJOR layout
// tb2[k>>3][row][k&7], row norms sq[], per-block column-sum / sum(sq)
// partials. 256 blocks, 8 rows/wave. No atomics/tickets/fences; every output
// word fully overwritten every call.
// ---------------------------------------------------------------------------
__global__ void prep_kernel(const float* __restrict__ src,
                            const float* __restrict__ tgt,
                            unsigned short* __restrict__ tb2,
                            float* __restrict__ sq,
                            float* __restrict__ colsum_part,  // [256][256]
                            double* __restrict__ sumsq_part)  // [256]
{
    __shared__ float colpart[4][256];
    __shared__ double wsum[4];
    int tid = threadIdx.x;
    int wv = tid >> 6, ln = tid & 63;
    int row0 = blockIdx.x * 32 + wv * 8;

    float cp0 = 0.f, cp1 = 0.f, cp2 = 0.f, cp3 = 0.f;
    double dsum = 0.0;

    for (int t = 0; t < 8; ++t) {
        int row = row0 + t;
        const float* p = (row < B_HALF) ? (src + (size_t)row * D)
                                        : (tgt + (size_t)(row - B_HALF) * D);
        float4 v = *(const float4*)(p + ln * 4);
        unsigned short b0 = f2bf(v.x), b1 = f2bf(v.y), b2 = f2bf(v.z), b3 = f2bf(v.w);
        float x0 = bf2f(b0), x1 = bf2f(b1), x2 = bf2f(b2), x3 = bf2f(b3);
        ushort4 u; u.x = b0; u.y = b1; u.z = b2; u.w = b3;
        // K-panel-major store: chunk = ln>>1, element base = (ln&1)*4
        *(ushort4*)(tb2 + ((size_t)(ln >> 1) * N_TOTAL + row) * 8 + (ln & 1) * 4) = u;

        cp0 += x0; cp1 += x1; cp2 += x2; cp3 += x3;

        float sqp = x0 * x0 + x1 * x1 + x2 * x2 + x3 * x3;
        #pragma unroll
        for (int off = 32; off; off >>= 1) sqp += __shfl_down(sqp, off, 64);
        if (ln == 0) { sq[row] = sqp; dsum += (double)sqp; }
    }
    colpart[wv][ln * 4 + 0] = cp0;
    colpart[wv][ln * 4 + 1] = cp1;
    colpart[wv][ln * 4 + 2] = cp2;
    colpart[wv][ln * 4 + 3] = cp3;
    if (ln == 0) wsum[wv] = dsum;
    __syncthreads();
    colsum_part[blockIdx.x * 256 + tid] =
        colpart[0][tid] + colpart[1][tid] + colpart[2][tid] + colpart[3][tid];
    if (tid == 0)
        sumsq_part[blockIdx.x] = wsum[0] + wsum[1] + wsum[2] + wsum[3];
}

// ---------------------------------------------------------------------------
// bw [r10-validated]: closed-form bandwidth from the partials.
//   sum(L2) = 2n*sum(sq) - 2*||colsum||^2 ; cexp = log2(e)/(16*bw)
// ---------------------------------------------------------------------------
__global__ void bw_kernel(const float* __restrict__ colsum_part,
                          const double* __restrict__ sumsq_part,
                          float* __restrict__ cexp) {
    __shared__ double red1[256], red2[256];
    int tid = threadIdx.x;
    float cs = 0.f;
    #pragma unroll 8
    for (int b = 0; b < PREP_BLOCKS; ++b)
        cs += colsum_part[b * 256 + tid];          // coalesced across threads
    red1[tid] = sumsq_part[tid];                   // 256 prep blocks
    red2[tid] = (double)cs * (double)cs;
    __syncthreads();
    for (int off = 128; off; off >>= 1) {
        if (tid < off) { red1[tid] += red1[tid + off]; red2[tid] += red2[tid + off]; }
        __syncthreads();
    }
    if (tid == 0) {
        double sl2 = 2.0 * (double)N_TOTAL * red1[0] - 2.0 * red2[0];
        double bw = sl2 / ((double)N_TOTAL * N_TOTAL - (double)N_TOTAL);
        cexp[0] = (float)(1.4426950408889634 / (16.0 * bw));
    }
}

// ---------------------------------------------------------------------------
// mmd [r15-validated, best per-tile measurement lineage (r11: 11.2 ns/tile)]:
// lower-triangle 128x128 Gram tiles (bijective XCD swizzle), direct-global
// K-panel fragment loads (1 KB contiguous per wave-load), 2-deep register
// prefetch, no LDS staging, no K-loop barriers, scalar fma+exp2 epilogue,
// plain partials store.
// ---------------------------------------------------------------------------
__global__ __launch_bounds__(256, 3)
void mmd_kernel(const unsigned short* __restrict__ tb2,
                const float* __restrict__ sq,
                const float* __restrict__ cexp_p,
                double* __restrict__ partials) {
    __shared__ float nsqi[BM], nsqj[BM];
    __shared__ float redbuf[4];

    // bijective XCD swizzle (2080 = 8 * 260), then triangle decode
    int bid = blockIdx.x;
    int t = (bid & 7) * (NBLK / 8) + (bid >> 3);
    int r = (int)((sqrtf(8.0f * (float)t + 1.0f) - 1.0f) * 0.5f);
    while ((r + 1) * (r + 2) / 2 <= t) ++r;
    while (r * (r + 1) / 2 > t) --r;
    int c = t - r * (r + 1) / 2;
    int rowBase = r * BM, colBase = c * BM;

    int tid = threadIdx.x;
    int wv = tid >> 6, ln = tid & 63;
    int wr = wv >> 1, wc = wv & 1;
    int lo = ln & 15, hi = ln >> 4;

    float cexp = cexp_p[0];
    // pre-negate and pre-scale: arg = fma(gram, 2*cexp, nsi + nsj) = -L2*cexp
    if (tid < BM) nsqi[tid] = -sq[rowBase + tid] * cexp;
    else          nsqj[tid - BM] = -sq[colBase + (tid - BM)] * cexp;
    __syncthreads();                 // only pre-epilogue barrier

    // fragment base pointers: frag(kk, f) at p + kk*KKSTRIDE + f*256B
    // (lane lo+16*hi: row = base + f*16 + lo, k-chunk = kk*4 + hi)
    const char* pa = (const char*)tb2 +
        ((size_t)hi * N_TOTAL + rowBase + wr * 64 + lo) * 16;
    const char* pb = (const char*)tb2 +
        ((size_t)hi * N_TOTAL + colBase + wc * 64 + lo) * 16;
    const size_t KKSTRIDE = (size_t)4 * N_TOTAL * 16;   // 512 KB

    f32x4v acc[4][4] = {};
    bf16x8v a[2][4], b[2][4];

    #pragma unroll
    for (int mi = 0; mi < 4; ++mi) a[0][mi] = *(const bf16x8v*)(pa + mi * 256);
    #pragma unroll
    for (int ni = 0; ni < 4; ++ni) b[0][ni] = *(const bf16x8v*)(pb + ni * 256);

    #pragma unroll
    for (int kk = 0; kk < 8; ++kk) {        // K = 8 x 32
        const int cur = kk & 1, nxt = cur ^ 1;
        if (kk < 7) {
            const char* qa = pa + (size_t)(kk + 1) * KKSTRIDE;
            const char* qb = pb + (size_t)(kk + 1) * KKSTRIDE;
            #pragma unroll
            for (int mi = 0; mi < 4; ++mi)
                a[nxt][mi] = *(const bf16x8v*)(qa + mi * 256);
            #pragma unroll
            for (int ni = 0; ni < 4; ++ni)
                b[nxt][ni] = *(const bf16x8v*)(qb + ni * 256);
        }
        __builtin_amdgcn_s_setprio(1);
        #pragma unroll
        for (int mi = 0; mi < 4; ++mi)
            #pragma unroll
            for (int ni = 0; ni < 4; ++ni)
                acc[mi][ni] = __builtin_amdgcn_mfma_f32_16x16x32_bf16(
                    a[cur][mi], b[cur][ni], acc[mi][ni], 0, 0, 0);
        __builtin_amdgcn_s_setprio(0);
    }

    // epilogue: arg = gram*2cexp + (nsi + nsj) ; sum = e0+e0^2+e0^4+e0^8+e0^16
    // C/D layout (16x16x32): col = lane&15, row = (lane>>4)*4 + reg
    float c2 = 2.0f * cexp;
    float tacc = 0.f;
    #pragma unroll
    for (int mi = 0; mi < 4; ++mi) {
        float si4[4];
        #pragma unroll
        for (int rg = 0; rg < 4; ++rg)
            si4[rg] = nsqi[wr * 64 + mi * 16 + hi * 4 + rg];
        #pragma unroll
        for (int ni = 0; ni < 4; ++ni) {
            float nsj = nsqj[wc * 64 + ni * 16 + lo];
            #pragma unroll
            for (int rg = 0; rg < 4; ++rg) {
                float arg = __builtin_fmaf(acc[mi][ni][rg], c2, si4[rg] + nsj);
                float e0 = __builtin_amdgcn_exp2f(arg);
                float e2 = e0 * e0, e4 = e2 * e2, e8 = e4 * e4, e16 = e8 * e8;
                tacc += (e0 + e2) + ((e4 + e8) + e16);
            }
        }
    }
    // tile-uniform sign (B_HALF multiple of BM) + triangle weight
    float w = ((r < NTILES / 2) == (c < NTILES / 2)) ? 1.f : -1.f;
    if (r != c) w *= 2.f;
    tacc *= w;

    // block reduction -> plain partial store (no fence, no atomic)
    #pragma unroll
    for (int off = 32; off; off >>= 1) tacc += __shfl_down(tacc, off, 64);
    if (ln == 0) redbuf[wv] = tacc;
    __syncthreads();
    if (tid == 0)
        partials[bid] =
            (double)(redbuf[0] + redbuf[1] + redbuf[2] + redbuf[3]);
}

// ---------------------------------------------------------------------------
__global__ void final_kernel(const double* __restrict__ partials,
                             float* __restrict__ out) {
    __shared__ double dred[256];
    int tid = threadIdx.x;
    double d = 0.0;
    for (int i = tid; i < NBLK; i += 256) d += partials[i];
    dred[tid] = d;
    __syncthreads();
    for (int off = 128; off; off >>= 1) {
        if (tid < off) dred[tid] += dred[tid + off];
        __syncthreads();
    }
    if (tid == 0)
        out[0] = (float)(dred[0] / (5.0 * (double)B_HALF * (double)B_HALF));
}

// ---------------------------------------------------------------------------
extern "C" void kernel_launch(void* const* d_in, const int* in_sizes, int n_in,
                              void* d_out, int out_size, void* d_ws, size_t ws_size,
                              hipStream_t stream) {
    const float* src = (const float*)d_in[0];
    const float* tgt = (const float*)d_in[1];
    float* out = (float*)d_out;
    char* ws = (char*)d_ws;

    // NO memset node, NO tickets, NO atomics: every ws word used is fully
    // overwritten every call before it is read.
    float*  cexp     = (float*)(ws + 192);
    double* ssqpart  = (double*)(ws + 2048);    // 256 f64  (ends 4096)
    float*  sq       = (float*)(ws + 8192);     // 8192 f32 (ends 40960)
    double* partials = (double*)(ws + 40960);   // 2080 f64 (ends 57600)
    float*  cspart   = (float*)(ws + 131072);   // 256*256 f32 (ends 393216)
    unsigned short* tb2 = (unsigned short*)(ws + 1048576);  // 4 MB bf16, K-panel-major

    prep_kernel<<<PREP_BLOCKS, 256, 0, stream>>>(src, tgt, tb2, sq, cspart,
                                                 ssqpart);
    bw_kernel<<<1, 256, 0, stream>>>(cspart, ssqpart, cexp);
    mmd_kernel<<<NBLK, 256, 0, stream>>>(tb2, sq, cexp, partials);
    final_kernel<<<1, 256, 0, stream>>>(partials, out);
}